// Round 12
// baseline (1779.475 us; speedup 1.0000x reference)
//
#include <hip/hip_runtime.h>
#include <hip/hip_bf16.h>

// RQV residual VQ — MFMA dist (16KB tiles, 4 blocks/CU) + r10 tail + fused logits.
// Inputs (fp32): data [16,256,2048], codebooks [8,1024,256], N_i [8,1024], m_i [8,1024,256]
// Outputs (fp32 concat): logits, loss, indices, new_N, new_m, new_W
// ws: AH/AL 2x16.78MB | whl 8.39MB | wnorm | rnorm | blockhist | rowlist | keybuf = 42,500,096 B

using f16   = _Float16;
using f16x4 = __attribute__((ext_vector_type(4))) _Float16;
using f16x8 = __attribute__((ext_vector_type(8))) _Float16;
using f32x4 = __attribute__((ext_vector_type(4))) float;
typedef unsigned long long u64;
typedef unsigned int u32;

#define GAMMA_F 0.99f
#define OMG_F   0.01f
#define LO_SCALE 1024.0f
#define LO_INV   (1.0f/1024.0f)

__device__ __forceinline__ void gload16(const void* g, void* l){
  __builtin_amdgcn_global_load_lds(
      (const __attribute__((address_space(1))) u32*)g,
      (__attribute__((address_space(3))) u32*)l, 16, 0, 0);
}

__global__ void sentinel_kernel(float* out, float v){
  if (threadIdx.x == 0 && blockIdx.x == 0) out[0] = v;
}

// ---------- codebook row norms ----------
__global__ __launch_bounds__(64) void rownorm_kernel(const float* __restrict__ X,
                                                     float* __restrict__ out, int rows){
  int r = blockIdx.x;
  if (r >= rows) return;
  int l = threadIdx.x;
  const float* x = X + (size_t)r * 256;
  float s = 0.f;
  #pragma unroll
  for (int i = 0; i < 4; i++){ float v = x[l + i*64]; s += v*v; }
  #pragma unroll
  for (int o = 32; o > 0; o >>= 1) s += __shfl_down(s, o, 64);
  if (l == 0) out[r] = s;
}

// ---------- codebook split into MFMA B-fragment order (verified) ----------
__global__ __launch_bounds__(64) void wsplit_kernel(const float* __restrict__ W,
                                                    f16* __restrict__ frag){
  int blk = blockIdx.x;                 // (q*64+ct)*8+kf
  int lane = threadIdx.x;
  int code = (blk >> 3 << 4) + (lane & 15);
  int k0   = (blk & 7)*32 + (lane >> 4)*8;
  const float* src = W + (size_t)code * 256 + k0;
  float4 a = *(const float4*)(src);
  float4 b = *(const float4*)(src + 4);
  float x[8] = {a.x,a.y,a.z,a.w, b.x,b.y,b.z,b.w};
  f16x8 h8, l8;
  #pragma unroll
  for (int i = 0; i < 8; i++){
    f16 h = (f16)x[i];
    h8[i] = h;
    l8[i] = (f16)((x[i] - (float)h) * LO_SCALE);
  }
  f16* dst = frag + (size_t)blk * 1024 + lane*8;
  *(f16x8*)dst         = h8;
  *(f16x8*)(dst + 512) = l8;
}

// ---------- init: data -> ROW-MAJOR fp16 hi/lo planes + rownorm ----------
__global__ __launch_bounds__(256) void init_kernel(const float* __restrict__ data,
                                                   f16* __restrict__ AH, f16* __restrict__ AL,
                                                   float* __restrict__ rnorm){
  __shared__ float rs[32][257];
  __shared__ float nrmp[32][8];
  int blk = blockIdx.x, b = blk >> 6, s0 = (blk & 63) * 32;
  int tid = threadIdx.x, c = tid & 31, g = tid >> 5;
  const float* dptr = data + (size_t)b * 524288 + s0;
  float np_ = 0.f;
  #pragma unroll 8
  for (int dd = 0; dd < 32; ++dd){
    int d = g*32 + dd;
    float x = dptr[(size_t)d * 2048 + c];
    rs[c][d] = x;
    np_ += x*x;
  }
  nrmp[c][g] = np_;
  __syncthreads();
  if (tid < 32){
    float s = 0.f;
    #pragma unroll
    for (int gg = 0; gg < 8; ++gg) s += nrmp[tid][gg];
    rnorm[blk*32 + tid] = s;
  }
  int r0 = blk*32;
  int c2 = tid >> 3, k0 = (tid & 7) * 32;
  #pragma unroll
  for (int jc = 0; jc < 4; ++jc){
    f16x8 h8, l8;
    #pragma unroll
    for (int j = 0; j < 8; ++j){
      float x = rs[c2][k0 + jc*8 + j];
      f16 h = (f16)x;
      h8[j] = h;
      l8[j] = (f16)((x - (float)h) * LO_SCALE);
    }
    size_t off = (size_t)(r0 + c2) * 256 + k0 + jc*8;
    *(f16x8*)(AH + off) = h8;
    *(f16x8*)(AL + off) = l8;
  }
}

// ---------- out4 = mi * gamma ----------
__global__ __launch_bounds__(256) void out4init_kernel(const float* __restrict__ mi,
                                                       float* __restrict__ out4){
  int e4 = blockIdx.x*256 + threadIdx.x;
  float4 v = ((const float4*)mi)[e4];
  v.x *= GAMMA_F; v.y *= GAMMA_F; v.z *= GAMMA_F; v.w *= GAMMA_F;
  ((float4*)out4)[e4] = v;
}

// ---------- dist: 16-code its, 16KB tiles dbuf, gload_lds, 4 blocks/CU ----------
__global__ __launch_bounds__(256, 4) void dist_kernel(
    const f16* __restrict__ AH, const f16* __restrict__ AL,
    const f16* __restrict__ whl, const float* __restrict__ wnorm,
    const float* __restrict__ rnorm, u64* __restrict__ keybuf, int q)
{
  __shared__ f16 Bs[2][8192];          // 1 ct (16 codes) hi+lo per buffer: 16 KB
  const int tid = threadIdx.x;
  const int lane = tid & 63;
  const int w = tid >> 6;
  const int rb = blockIdx.x, cs = blockIdx.y;
  const int rlo = lane & 15, kg = lane >> 4;
  const int T0 = rb*8 + w*2;

  // A fragments (32 rows, hi/lo) from row-major planes — coalesced
  f16x8 aH[2][8], aL[2][8];
  #pragma unroll
  for (int rt = 0; rt < 2; ++rt)
    #pragma unroll
    for (int kf = 0; kf < 8; ++kf){
      size_t off = (size_t)((T0+rt)*16 + rlo) * 256 + kf*32 + kg*8;
      aH[rt][kf] = *(const f16x8*)(AH + off);
      aL[rt][kf] = *(const f16x8*)(AL + off);
    }
  float rn[2][4];
  #pragma unroll
  for (int rt = 0; rt < 2; ++rt)
    #pragma unroll
    for (int i = 0; i < 4; ++i)
      rn[rt][i] = rnorm[(T0+rt)*16 + kg*4 + i];

  const f16* wb = whl + (size_t)q * 524288;
  const float* wn = wnorm + (q << 10);
  const int ct0 = cs * 16;             // 16 cts (codes) per cs-block

  float bestv[8]; int besti[8];
  #pragma unroll
  for (int r8_ = 0; r8_ < 8; ++r8_){ bestv[r8_] = 3.4e38f; besti[r8_] = 0; }

  // prologue: stage ct0 tile (16 KB): wave w stages f16-range [w*2048, w*2048+2048)
  {
    const f16* src = wb + (size_t)ct0 * 8192 + w*2048 + lane*8;
    f16* dst = &Bs[0][0] + w*2048;
    #pragma unroll
    for (int j = 0; j < 4; ++j)
      gload16(src + j*512, dst + j*512);
  }

  for (int it = 0; it < 16; ++it){
    int ct = ct0 + it;
    __syncthreads();                   // drains gload_lds: Bs[it&1] ready
    if (it < 15){
      const f16* src = wb + (size_t)(ct+1) * 8192 + w*2048 + lane*8;
      f16* dst = &Bs[(it+1) & 1][0] + w*2048;
      #pragma unroll
      for (int j = 0; j < 4; ++j)
        gload16(src + j*512, dst + j*512);
    }
    const f16* bb = &Bs[it & 1][0];
    f32x4 hh[2], cr[2];
    #pragma unroll
    for (int rt = 0; rt < 2; ++rt){ hh[rt] = (f32x4)0.0f; cr[rt] = (f32x4)0.0f; }
    __builtin_amdgcn_s_setprio(1);
    #pragma unroll
    for (int kf = 0; kf < 8; ++kf){
      f16x8 bh = *(const f16x8*)(bb + kf*1024 + lane*8);
      f16x8 bl = *(const f16x8*)(bb + kf*1024 + 512 + lane*8);
      hh[0] = __builtin_amdgcn_mfma_f32_16x16x32_f16(aH[0][kf], bh, hh[0], 0,0,0);
      cr[0] = __builtin_amdgcn_mfma_f32_16x16x32_f16(aH[0][kf], bl, cr[0], 0,0,0);
      cr[0] = __builtin_amdgcn_mfma_f32_16x16x32_f16(aL[0][kf], bh, cr[0], 0,0,0);
      hh[1] = __builtin_amdgcn_mfma_f32_16x16x32_f16(aH[1][kf], bh, hh[1], 0,0,0);
      cr[1] = __builtin_amdgcn_mfma_f32_16x16x32_f16(aH[1][kf], bl, cr[1], 0,0,0);
      cr[1] = __builtin_amdgcn_mfma_f32_16x16x32_f16(aL[1][kf], bh, cr[1], 0,0,0);
    }
    __builtin_amdgcn_s_setprio(0);
    int code = (ct << 4) + rlo;
    float wnc = wn[code];
    #pragma unroll
    for (int rt = 0; rt < 2; ++rt)
      #pragma unroll
      for (int i = 0; i < 4; ++i){
        float dot = hh[rt][i] + cr[rt][i] * LO_INV;
        float d2 = (rn[rt][i] + wnc) - 2.0f * dot;
        int r8_ = rt*4 + i;
        if (d2 < bestv[r8_] || (d2 == bestv[r8_] && code < besti[r8_])){
          bestv[r8_] = d2; besti[r8_] = code;
        }
      }
  }

  // reduce across the 16 code-lanes (first-min, lowest index)
  #pragma unroll
  for (int off = 1; off <= 8; off <<= 1){
    #pragma unroll
    for (int r8_ = 0; r8_ < 8; ++r8_){
      float ov = __shfl_xor(bestv[r8_], off, 16);
      int   oi = __shfl_xor(besti[r8_], off, 16);
      if (ov < bestv[r8_] || (ov == bestv[r8_] && oi < besti[r8_])){
        bestv[r8_] = ov; besti[r8_] = oi;
      }
    }
  }
  if (rlo == 0){
    #pragma unroll
    for (int r8_ = 0; r8_ < 8; ++r8_){
      int rt = r8_ >> 2, i = r8_ & 3;
      int grow = (T0 + rt)*16 + kg*4 + i;
      unsigned fb = __float_as_uint(bestv[r8_]);
      fb = (fb & 0x80000000u) ? ~fb : (fb | 0x80000000u);   // monotone sortable
      u64 key = ((u64)fb << 32) | (unsigned)besti[r8_];
      atomicMin(keybuf + grow, key);
    }
  }
}

// ---------- hist: extract codes from keys, per-block histogram, reset keybuf ----------
__global__ __launch_bounds__(256) void hist_kernel(u64* __restrict__ keybuf,
                                                   float* __restrict__ out2q,
                                                   unsigned short* __restrict__ blockhist){
  __shared__ int h[1024];
  int tid = threadIdx.x, b = blockIdx.x;
  #pragma unroll
  for (int i = 0; i < 4; ++i) h[tid + 256*i] = 0;
  __syncthreads();
  #pragma unroll
  for (int j = 0; j < 4; ++j){
    int row = b*1024 + tid + 256*j;
    u64 k = keybuf[row];
    keybuf[row] = ~0ull;               // reset for next stage
    int c = (int)(k & 0xFFFF);
    out2q[row] = (float)c;
    atomicAdd(&h[c], 1);
  }
  __syncthreads();
  #pragma unroll
  for (int i = 0; i < 4; ++i)
    blockhist[b*1024 + tid + 256*i] = (unsigned short)h[tid + 256*i];
}

// ---------- fused scan + scatter (32 blocks, redundant scan) + new_N ----------
__global__ __launch_bounds__(256) void scanscatter_kernel(
    const unsigned short* __restrict__ blockhist, const float* __restrict__ out2q,
    unsigned short* __restrict__ rowlist, const float* __restrict__ Ni,
    float* __restrict__ out3, int q)
{
  __shared__ int wtot[4];
  __shared__ int cur[1024];
  int tid = threadIdx.x, b = blockIdx.x, lane = tid & 63, w = tid >> 6;
  const ushort4* bh4 = (const ushort4*)blockhist;
  int tot[4] = {0,0,0,0}, pre[4] = {0,0,0,0};
  for (int bb = 0; bb < 32; ++bb){
    ushort4 h = bh4[bb*256 + tid];
    if (bb < b){ pre[0]+=h.x; pre[1]+=h.y; pre[2]+=h.z; pre[3]+=h.w; }
    tot[0]+=h.x; tot[1]+=h.y; tot[2]+=h.z; tot[3]+=h.w;
  }
  int s = tot[0]+tot[1]+tot[2]+tot[3];
  int v = s;
  #pragma unroll
  for (int d = 1; d < 64; d <<= 1){
    int o = __shfl_up(v, d, 64);
    if (lane >= d) v += o;
  }
  if (lane == 63) wtot[w] = v;
  __syncthreads();
  int woff = 0;
  #pragma unroll
  for (int ww = 0; ww < 4; ++ww) if (ww < w) woff += wtot[ww];
  int base = woff + v - s;             // global exclusive prefix for code 4*tid
  if (b == 0){
    const int qb = q << 10;
    out3[qb + 4*tid+0] = Ni[qb + 4*tid+0]*GAMMA_F + (float)tot[0]*OMG_F;
    out3[qb + 4*tid+1] = Ni[qb + 4*tid+1]*GAMMA_F + (float)tot[1]*OMG_F;
    out3[qb + 4*tid+2] = Ni[qb + 4*tid+2]*GAMMA_F + (float)tot[2]*OMG_F;
    out3[qb + 4*tid+3] = Ni[qb + 4*tid+3]*GAMMA_F + (float)tot[3]*OMG_F;
  }
  cur[4*tid+0] = base + pre[0];
  cur[4*tid+1] = base + tot[0] + pre[1];
  cur[4*tid+2] = base + tot[0]+tot[1] + pre[2];
  cur[4*tid+3] = base + tot[0]+tot[1]+tot[2] + pre[3];
  __syncthreads();
  #pragma unroll
  for (int j = 0; j < 4; ++j){
    int row = b*1024 + tid + 256*j;
    int c = (int)out2q[row];
    int pos = atomicAdd(&cur[c], 1);
    rowlist[pos] = (unsigned short)row;
  }
}

// ---------- update: 2048 1-wave blocks, 16 slots, 2-deep prefetch ----------
// LAST=1 (q=7): skip residual writeback + rnorm (logits kernel applies final subtract).
template<int LAST>
__global__ __launch_bounds__(64) void update_kernel(
    f16* __restrict__ AH, f16* __restrict__ AL,
    const unsigned short* __restrict__ rowlist, const float* __restrict__ out2q,
    const float* __restrict__ codebooks, float* __restrict__ out4,
    float* __restrict__ rnorm, int q)
{
  const int lane = threadIdx.x;
  const int s0 = blockIdx.x * 16;
  int myrow = 0, mycode = 0;
  if (lane < 16){
    myrow = rowlist[s0 + lane];
    mycode = (int)out2q[myrow];
  }
  float vs[4] = {0.f, 0.f, 0.f, 0.f};
  float Wk[4] = {0.f, 0.f, 0.f, 0.f};
  int prev = -1;
  int rowp = __shfl(myrow, 0, 64);
  f16x4 ph = *(const f16x4*)(AH + (size_t)rowp*256 + lane*4);
  f16x4 pl = *(const f16x4*)(AL + (size_t)rowp*256 + lane*4);
  for (int s = 0; s < 16; ++s){
    int row  = __shfl(myrow, s, 64);
    int code = __shfl(mycode, s, 64);
    f16x4 h4 = ph, l4 = pl;
    if (s < 15){
      int rown = __shfl(myrow, s+1, 64);
      ph = *(const f16x4*)(AH + (size_t)rown*256 + lane*4);
      pl = *(const f16x4*)(AL + (size_t)rown*256 + lane*4);
    }
    if (code != prev){
      if (prev >= 0){
        float* dst = out4 + (((size_t)q << 10) + prev)*256 + lane*4;
        #pragma unroll
        for (int t = 0; t < 4; ++t) atomicAdd(dst + t, vs[t] * OMG_F);
      }
      if (!LAST){
        float4 wv = *(const float4*)&codebooks[(((size_t)q << 10) + code)*256 + lane*4];
        Wk[0] = wv.x; Wk[1] = wv.y; Wk[2] = wv.z; Wk[3] = wv.w;
      }
      vs[0] = vs[1] = vs[2] = vs[3] = 0.f;
      prev = code;
    }
    float p = 0.f;
    f16x4 nh, nl;
    #pragma unroll
    for (int t = 0; t < 4; ++t){
      float rj = (float)h4[t] + (float)l4[t] * LO_INV;
      vs[t] += rj;
      if (!LAST){
        float rn_ = rj - Wk[t];
        f16 hh = (f16)rn_;
        nh[t] = hh;
        nl[t] = (f16)((rn_ - (float)hh) * LO_SCALE);
        p += rn_ * rn_;
      }
    }
    if (!LAST){
      size_t base = (size_t)row * 256 + lane*4;
      *(f16x4*)(AH + base) = nh;
      *(f16x4*)(AL + base) = nl;
      #pragma unroll
      for (int o = 32; o > 0; o >>= 1) p += __shfl_down(p, o, 64);
      if (lane == 0) rnorm[row] = p;
    }
  }
  if (prev >= 0){
    float* dst = out4 + (((size_t)q << 10) + prev)*256 + lane*4;
    #pragma unroll
    for (int t = 0; t < 4; ++t) atomicAdd(dst + t, vs[t] * OMG_F);
  }
}

// ---------- epilogue: logits = data - (r7 - W7[c7]), loss ----------
__global__ __launch_bounds__(256) void logits_loss_kernel(
    const float* __restrict__ data, const f16* __restrict__ AH, const f16* __restrict__ AL,
    const float* __restrict__ out2q7, const float* __restrict__ W7,
    float* __restrict__ out0, float* __restrict__ out1)
{
  __shared__ float rs[32][257];
  int blk = blockIdx.x, b = blk >> 6, s0 = (blk & 63) * 32;
  int tid = threadIdx.x;
  int r0 = blk*32;
  int c2 = tid >> 3, k0 = (tid & 7) * 32;
  int grow = r0 + c2;
  int code = (int)out2q7[grow];
  const float* wrow = W7 + (size_t)code * 256 + k0;
  #pragma unroll
  for (int jc = 0; jc < 4; ++jc){
    size_t off = (size_t)grow * 256 + k0 + jc*8;
    f16x8 h8 = *(const f16x8*)(AH + off);
    f16x8 l8 = *(const f16x8*)(AL + off);
    float4 w0 = *(const float4*)(wrow + jc*8);
    float4 w1 = *(const float4*)(wrow + jc*8 + 4);
    float wv[8] = {w0.x,w0.y,w0.z,w0.w, w1.x,w1.y,w1.z,w1.w};
    #pragma unroll
    for (int j = 0; j < 8; ++j)
      rs[c2][k0 + jc*8 + j] = ((float)h8[j] + (float)l8[j] * LO_INV) - wv[j];
  }
  __syncthreads();
  int c = tid & 31, g = tid >> 5;
  const float* dptr = data + (size_t)b * 524288 + s0;
  float* optr = out0 + (size_t)b * 524288 + s0;
  float lsum = 0.f;
  #pragma unroll 8
  for (int dd = 0; dd < 32; ++dd){
    int d = g*32 + dd;
    float r = rs[c][d];
    lsum += r*r;
    optr[(size_t)d * 2048 + c] = dptr[(size_t)d * 2048 + c] - r;
  }
  #pragma unroll
  for (int o = 32; o > 0; o >>= 1) lsum += __shfl_down(lsum, o, 64);
  if ((tid & 63) == 0) atomicAdd(out1, lsum * (1.0f / 8388608.0f));
}

// ---------- final: new_W = new_m / clip(new_N) ----------
__global__ __launch_bounds__(256) void out5_kernel(const float* __restrict__ out4,
                                                   const float* __restrict__ out3,
                                                   float* __restrict__ out5){
  int e4 = blockIdx.x*256 + threadIdx.x;
  float Nn = fmaxf(out3[e4 >> 6], 1e-8f);
  float4 v = ((const float4*)out4)[e4];
  v.x /= Nn; v.y /= Nn; v.z /= Nn; v.w /= Nn;
  ((float4*)out5)[e4] = v;
}

extern "C" void kernel_launch(void* const* d_in, const int* in_sizes, int n_in,
                              void* d_out, int out_size, void* d_ws, size_t ws_size,
                              hipStream_t stream){
  float* out = (float*)d_out;

  // size-keyed input binding
  const float* data = nullptr; const float* codebooks = nullptr;
  const float* Ni = nullptr;   const float* mi = nullptr;
  for (int i = 0; i < n_in; ++i){
    if      (in_sizes[i] == 8388608) data = (const float*)d_in[i];
    else if (in_sizes[i] == 8192)    Ni   = (const float*)d_in[i];
    else if (in_sizes[i] == 2097152){
      if (!codebooks) codebooks = (const float*)d_in[i];
      else            mi        = (const float*)d_in[i];
    }
  }
  if (!data || !codebooks || !Ni || !mi){
    sentinel_kernel<<<1, 64, 0, stream>>>(out, 6666.0f);
    return;
  }

  // ws layout (bytes):
  // AH 16,777,216 | AL 16,777,216 | whl 8,388,608 | wnorm 32,768 | rnorm 131,072 |
  // blockhist 65,536 | rowlist 65,536 | keybuf 262,144 = 42,500,096
  const size_t ws_need = 42500096ull;
  if (ws_size < ws_need){
    sentinel_kernel<<<1, 64, 0, stream>>>(out, 7777.0f);
    return;
  }
  f16*   AH     = (f16*)d_ws;
  f16*   AL     = AH + 8388608;
  f16*   whl    = AL + 8388608;
  float* wnormb = (float*)(whl + 4194304);
  float* rnorm  = wnormb + 8192;
  unsigned short* blockhist = (unsigned short*)(rnorm + 32768);
  unsigned short* rowlist   = blockhist + 32768;
  u64*   keybuf = (u64*)(rowlist + 32768);

  // out offsets (fp32, reference return order)
  float* out0 = out;                  // logits  8388608
  float* out1 = out0 + 8388608;       // loss    1
  float* out2 = out1 + 1;             // indices 262144
  float* out3 = out2 + 262144;        // new_N   8192
  float* out4 = out3 + 8192;          // new_m   2097152
  float* out5 = out4 + 2097152;       // new_W   2097152

  hipMemsetAsync(out1, 0, sizeof(float), stream);
  hipMemsetAsync(keybuf, 0xFF, 262144, stream);

  wsplit_kernel<<<dim3(4096), 64, 0, stream>>>(codebooks, whl);
  rownorm_kernel<<<dim3(8192), 64, 0, stream>>>(codebooks, wnormb, 8192);
  init_kernel<<<dim3(1024), 256, 0, stream>>>(data, AH, AL, rnorm);
  out4init_kernel<<<dim3(2048), 256, 0, stream>>>(mi, out4);

  for (int q = 0; q < 8; ++q){
    float* out2q = out2 + (size_t)q * 32768;
    dist_kernel<<<dim3(256, 4), 256, 0, stream>>>(AH, AL, whl, wnormb, rnorm, keybuf, q);
    hist_kernel<<<dim3(32), 256, 0, stream>>>(keybuf, out2q, blockhist);
    scanscatter_kernel<<<dim3(32), 256, 0, stream>>>(blockhist, out2q, rowlist,
                                                     Ni, out3, q);
    if (q < 7)
      update_kernel<0><<<dim3(2048), 64, 0, stream>>>(AH, AL, rowlist, out2q,
                                                      codebooks, out4, rnorm, q);
    else
      update_kernel<1><<<dim3(2048), 64, 0, stream>>>(AH, AL, rowlist, out2q,
                                                      codebooks, out4, rnorm, q);
  }

  logits_loss_kernel<<<dim3(1024), 256, 0, stream>>>(data, AH, AL,
                                                     out2 + 7*32768,
                                                     codebooks + 7*262144,
                                                     out0, out1);
  out5_kernel<<<dim3(2048), 256, 0, stream>>>(out4, out3, out5);
}

// Round 13
// 900.136 us; speedup vs baseline: 1.9769x; 1.9769x over previous
//
#include <hip/hip_runtime.h>
#include <hip/hip_bf16.h>

// RQV residual VQ — MFMA dist (3-ring counted-vmcnt pipeline) + r12 tail.
// Inputs (fp32): data [16,256,2048], codebooks [8,1024,256], N_i [8,1024], m_i [8,1024,256]
// Outputs (fp32 concat): logits, loss, indices, new_N, new_m, new_W
// ws: AH/AL 2x16.78MB | whl 8.39MB | wnorm | rnorm | blockhist | rowlist | keybuf = 42,500,096 B

using f16   = _Float16;
using f16x4 = __attribute__((ext_vector_type(4))) _Float16;
using f16x8 = __attribute__((ext_vector_type(8))) _Float16;
using f32x4 = __attribute__((ext_vector_type(4))) float;
typedef unsigned long long u64;
typedef unsigned int u32;

#define GAMMA_F 0.99f
#define OMG_F   0.01f
#define LO_SCALE 1024.0f
#define LO_INV   (1.0f/1024.0f)

__device__ __forceinline__ void gload16(const void* g, void* l){
  __builtin_amdgcn_global_load_lds(
      (const __attribute__((address_space(1))) u32*)g,
      (__attribute__((address_space(3))) u32*)l, 16, 0, 0);
}

__global__ void sentinel_kernel(float* out, float v){
  if (threadIdx.x == 0 && blockIdx.x == 0) out[0] = v;
}

// ---------- codebook row norms ----------
__global__ __launch_bounds__(64) void rownorm_kernel(const float* __restrict__ X,
                                                     float* __restrict__ out, int rows){
  int r = blockIdx.x;
  if (r >= rows) return;
  int l = threadIdx.x;
  const float* x = X + (size_t)r * 256;
  float s = 0.f;
  #pragma unroll
  for (int i = 0; i < 4; i++){ float v = x[l + i*64]; s += v*v; }
  #pragma unroll
  for (int o = 32; o > 0; o >>= 1) s += __shfl_down(s, o, 64);
  if (l == 0) out[r] = s;
}

// ---------- codebook split into MFMA B-fragment order (verified) ----------
__global__ __launch_bounds__(64) void wsplit_kernel(const float* __restrict__ W,
                                                    f16* __restrict__ frag){
  int blk = blockIdx.x;                 // (q*64+ct)*8+kf
  int lane = threadIdx.x;
  int code = (blk >> 3 << 4) + (lane & 15);
  int k0   = (blk & 7)*32 + (lane >> 4)*8;
  const float* src = W + (size_t)code * 256 + k0;
  float4 a = *(const float4*)(src);
  float4 b = *(const float4*)(src + 4);
  float x[8] = {a.x,a.y,a.z,a.w, b.x,b.y,b.z,b.w};
  f16x8 h8, l8;
  #pragma unroll
  for (int i = 0; i < 8; i++){
    f16 h = (f16)x[i];
    h8[i] = h;
    l8[i] = (f16)((x[i] - (float)h) * LO_SCALE);
  }
  f16* dst = frag + (size_t)blk * 1024 + lane*8;
  *(f16x8*)dst         = h8;
  *(f16x8*)(dst + 512) = l8;
}

// ---------- init: data -> ROW-MAJOR fp16 hi/lo planes + rownorm ----------
__global__ __launch_bounds__(256) void init_kernel(const float* __restrict__ data,
                                                   f16* __restrict__ AH, f16* __restrict__ AL,
                                                   float* __restrict__ rnorm){
  __shared__ float rs[32][257];
  __shared__ float nrmp[32][8];
  int blk = blockIdx.x, b = blk >> 6, s0 = (blk & 63) * 32;
  int tid = threadIdx.x, c = tid & 31, g = tid >> 5;
  const float* dptr = data + (size_t)b * 524288 + s0;
  float np_ = 0.f;
  #pragma unroll 8
  for (int dd = 0; dd < 32; ++dd){
    int d = g*32 + dd;
    float x = dptr[(size_t)d * 2048 + c];
    rs[c][d] = x;
    np_ += x*x;
  }
  nrmp[c][g] = np_;
  __syncthreads();
  if (tid < 32){
    float s = 0.f;
    #pragma unroll
    for (int gg = 0; gg < 8; ++gg) s += nrmp[tid][gg];
    rnorm[blk*32 + tid] = s;
  }
  int r0 = blk*32;
  int c2 = tid >> 3, k0 = (tid & 7) * 32;
  #pragma unroll
  for (int jc = 0; jc < 4; ++jc){
    f16x8 h8, l8;
    #pragma unroll
    for (int j = 0; j < 8; ++j){
      float x = rs[c2][k0 + jc*8 + j];
      f16 h = (f16)x;
      h8[j] = h;
      l8[j] = (f16)((x - (float)h) * LO_SCALE);
    }
    size_t off = (size_t)(r0 + c2) * 256 + k0 + jc*8;
    *(f16x8*)(AH + off) = h8;
    *(f16x8*)(AL + off) = l8;
  }
}

// ---------- out4 = mi * gamma ----------
__global__ __launch_bounds__(256) void out4init_kernel(const float* __restrict__ mi,
                                                       float* __restrict__ out4){
  int e4 = blockIdx.x*256 + threadIdx.x;
  float4 v = ((const float4*)mi)[e4];
  v.x *= GAMMA_F; v.y *= GAMMA_F; v.z *= GAMMA_F; v.w *= GAMMA_F;
  ((float4*)out4)[e4] = v;
}

// ---------- dist: 16-code tiles, 3-ring gload_lds, counted vmcnt (T4) ----------
__global__ __launch_bounds__(256, 2) void dist_kernel(
    const f16* __restrict__ AH, const f16* __restrict__ AL,
    const f16* __restrict__ whl, const float* __restrict__ wnorm,
    const float* __restrict__ rnorm, u64* __restrict__ keybuf, int q)
{
  __shared__ f16 Bs[3][8192];          // 16-code tile (bh+bl) per buffer: 16 KB x 3
  const int tid = threadIdx.x;
  const int lane = tid & 63;
  const int w = tid >> 6;
  const int rb = blockIdx.x, cs = blockIdx.y;
  const int rlo = lane & 15, kg = lane >> 4;
  const int T0 = rb*8 + w*2;

  // A fragments (32 rows, hi/lo) from row-major planes — coalesced
  f16x8 aH[2][8], aL[2][8];
  #pragma unroll
  for (int rt = 0; rt < 2; ++rt)
    #pragma unroll
    for (int kf = 0; kf < 8; ++kf){
      size_t off = (size_t)((T0+rt)*16 + rlo) * 256 + kf*32 + kg*8;
      aH[rt][kf] = *(const f16x8*)(AH + off);
      aL[rt][kf] = *(const f16x8*)(AL + off);
    }
  float rn[2][4];
  #pragma unroll
  for (int rt = 0; rt < 2; ++rt)
    #pragma unroll
    for (int i = 0; i < 4; ++i)
      rn[rt][i] = rnorm[(T0+rt)*16 + kg*4 + i];

  const f16* wb = whl + (size_t)q * 524288;
  const float* wn = wnorm + (q << 10);
  const int ct0 = cs * 16;             // 16 tiles (cts) per cs-block

  float bestv[8]; int besti[8];
  #pragma unroll
  for (int r8_ = 0; r8_ < 8; ++r8_){ bestv[r8_] = 3.4e38f; besti[r8_] = 0; }

  // wave-quarter staging of one 16 KB tile = 4 gload16 per wave
  auto issue = [&](int buf, int ct_){
    const f16* src = wb + (size_t)ct_ * 8192 + w*2048 + lane*8;
    f16* dst = &Bs[buf][0] + w*2048;
    #pragma unroll
    for (int j = 0; j < 4; ++j)
      gload16(src + j*512, dst + j*512);
  };

  // prologue: tiles 0,1 in flight (8 vmem ops/wave)
  issue(0, ct0 + 0);
  issue(1, ct0 + 1);

  for (int it = 0; it < 16; ++it){
    // counted wait: tile `it` landed; tile `it+1`'s 4 loads may stay in flight
    if (it < 15) asm volatile("s_waitcnt vmcnt(4)" ::: "memory");
    else         asm volatile("s_waitcnt vmcnt(0)" ::: "memory");
    __builtin_amdgcn_sched_barrier(0);
    __builtin_amdgcn_s_barrier();      // all waves: tile `it` visible; tile `it-1` compute done
    __builtin_amdgcn_sched_barrier(0);
    if (it < 14) issue((it + 2) % 3, ct0 + it + 2);   // reuse buffer of tile it-1

    const f16* bb = &Bs[it % 3][0];
    f32x4 hh[2], cr[2];
    #pragma unroll
    for (int rt = 0; rt < 2; ++rt){ hh[rt] = (f32x4)0.0f; cr[rt] = (f32x4)0.0f; }
    __builtin_amdgcn_s_setprio(1);
    #pragma unroll
    for (int kf = 0; kf < 8; ++kf){
      f16x8 bh = *(const f16x8*)(bb + kf*1024 + lane*8);
      f16x8 bl = *(const f16x8*)(bb + kf*1024 + 512 + lane*8);
      hh[0] = __builtin_amdgcn_mfma_f32_16x16x32_f16(aH[0][kf], bh, hh[0], 0,0,0);
      cr[0] = __builtin_amdgcn_mfma_f32_16x16x32_f16(aH[0][kf], bl, cr[0], 0,0,0);
      cr[0] = __builtin_amdgcn_mfma_f32_16x16x32_f16(aL[0][kf], bh, cr[0], 0,0,0);
      hh[1] = __builtin_amdgcn_mfma_f32_16x16x32_f16(aH[1][kf], bh, hh[1], 0,0,0);
      cr[1] = __builtin_amdgcn_mfma_f32_16x16x32_f16(aH[1][kf], bl, cr[1], 0,0,0);
      cr[1] = __builtin_amdgcn_mfma_f32_16x16x32_f16(aL[1][kf], bh, cr[1], 0,0,0);
    }
    __builtin_amdgcn_s_setprio(0);
    int code = ((ct0 + it) << 4) + rlo;
    float wnc = wn[code];
    #pragma unroll
    for (int rt = 0; rt < 2; ++rt)
      #pragma unroll
      for (int i = 0; i < 4; ++i){
        float dot = hh[rt][i] + cr[rt][i] * LO_INV;
        float d2 = (rn[rt][i] + wnc) - 2.0f * dot;
        int r8_ = rt*4 + i;
        if (d2 < bestv[r8_] || (d2 == bestv[r8_] && code < besti[r8_])){
          bestv[r8_] = d2; besti[r8_] = code;
        }
      }
  }

  // reduce across the 16 code-lanes (first-min, lowest index)
  #pragma unroll
  for (int off = 1; off <= 8; off <<= 1){
    #pragma unroll
    for (int r8_ = 0; r8_ < 8; ++r8_){
      float ov = __shfl_xor(bestv[r8_], off, 16);
      int   oi = __shfl_xor(besti[r8_], off, 16);
      if (ov < bestv[r8_] || (ov == bestv[r8_] && oi < besti[r8_])){
        bestv[r8_] = ov; besti[r8_] = oi;
      }
    }
  }
  if (rlo == 0){
    #pragma unroll
    for (int r8_ = 0; r8_ < 8; ++r8_){
      int rt = r8_ >> 2, i = r8_ & 3;
      int grow = (T0 + rt)*16 + kg*4 + i;
      unsigned fb = __float_as_uint(bestv[r8_]);
      fb = (fb & 0x80000000u) ? ~fb : (fb | 0x80000000u);   // monotone sortable
      u64 key = ((u64)fb << 32) | (unsigned)besti[r8_];
      atomicMin(keybuf + grow, key);
    }
  }
}

// ---------- hist: extract codes from keys, per-block histogram, reset keybuf ----------
__global__ __launch_bounds__(256) void hist_kernel(u64* __restrict__ keybuf,
                                                   float* __restrict__ out2q,
                                                   unsigned short* __restrict__ blockhist){
  __shared__ int h[1024];
  int tid = threadIdx.x, b = blockIdx.x;
  #pragma unroll
  for (int i = 0; i < 4; ++i) h[tid + 256*i] = 0;
  __syncthreads();
  #pragma unroll
  for (int j = 0; j < 4; ++j){
    int row = b*1024 + tid + 256*j;
    u64 k = keybuf[row];
    keybuf[row] = ~0ull;               // reset for next stage
    int c = (int)(k & 0xFFFF);
    out2q[row] = (float)c;
    atomicAdd(&h[c], 1);
  }
  __syncthreads();
  #pragma unroll
  for (int i = 0; i < 4; ++i)
    blockhist[b*1024 + tid + 256*i] = (unsigned short)h[tid + 256*i];
}

// ---------- fused scan + scatter (32 blocks, redundant scan) + new_N ----------
__global__ __launch_bounds__(256) void scanscatter_kernel(
    const unsigned short* __restrict__ blockhist, const float* __restrict__ out2q,
    unsigned short* __restrict__ rowlist, const float* __restrict__ Ni,
    float* __restrict__ out3, int q)
{
  __shared__ int wtot[4];
  __shared__ int cur[1024];
  int tid = threadIdx.x, b = blockIdx.x, lane = tid & 63, w = tid >> 6;
  const ushort4* bh4 = (const ushort4*)blockhist;
  int tot[4] = {0,0,0,0}, pre[4] = {0,0,0,0};
  for (int bb = 0; bb < 32; ++bb){
    ushort4 h = bh4[bb*256 + tid];
    if (bb < b){ pre[0]+=h.x; pre[1]+=h.y; pre[2]+=h.z; pre[3]+=h.w; }
    tot[0]+=h.x; tot[1]+=h.y; tot[2]+=h.z; tot[3]+=h.w;
  }
  int s = tot[0]+tot[1]+tot[2]+tot[3];
  int v = s;
  #pragma unroll
  for (int d = 1; d < 64; d <<= 1){
    int o = __shfl_up(v, d, 64);
    if (lane >= d) v += o;
  }
  if (lane == 63) wtot[w] = v;
  __syncthreads();
  int woff = 0;
  #pragma unroll
  for (int ww = 0; ww < 4; ++ww) if (ww < w) woff += wtot[ww];
  int base = woff + v - s;             // global exclusive prefix for code 4*tid
  if (b == 0){
    const int qb = q << 10;
    out3[qb + 4*tid+0] = Ni[qb + 4*tid+0]*GAMMA_F + (float)tot[0]*OMG_F;
    out3[qb + 4*tid+1] = Ni[qb + 4*tid+1]*GAMMA_F + (float)tot[1]*OMG_F;
    out3[qb + 4*tid+2] = Ni[qb + 4*tid+2]*GAMMA_F + (float)tot[2]*OMG_F;
    out3[qb + 4*tid+3] = Ni[qb + 4*tid+3]*GAMMA_F + (float)tot[3]*OMG_F;
  }
  cur[4*tid+0] = base + pre[0];
  cur[4*tid+1] = base + tot[0] + pre[1];
  cur[4*tid+2] = base + tot[0]+tot[1] + pre[2];
  cur[4*tid+3] = base + tot[0]+tot[1]+tot[2] + pre[3];
  __syncthreads();
  #pragma unroll
  for (int j = 0; j < 4; ++j){
    int row = b*1024 + tid + 256*j;
    int c = (int)out2q[row];
    int pos = atomicAdd(&cur[c], 1);
    rowlist[pos] = (unsigned short)row;
  }
}

// ---------- update: 2048 1-wave blocks, 16 slots, 2-deep prefetch ----------
// LAST=1 (q=7): skip residual writeback + rnorm (logits kernel applies final subtract).
template<int LAST>
__global__ __launch_bounds__(64) void update_kernel(
    f16* __restrict__ AH, f16* __restrict__ AL,
    const unsigned short* __restrict__ rowlist, const float* __restrict__ out2q,
    const float* __restrict__ codebooks, float* __restrict__ out4,
    float* __restrict__ rnorm, int q)
{
  const int lane = threadIdx.x;
  const int s0 = blockIdx.x * 16;
  int myrow = 0, mycode = 0;
  if (lane < 16){
    myrow = rowlist[s0 + lane];
    mycode = (int)out2q[myrow];
  }
  float vs[4] = {0.f, 0.f, 0.f, 0.f};
  float Wk[4] = {0.f, 0.f, 0.f, 0.f};
  int prev = -1;
  int rowp = __shfl(myrow, 0, 64);
  f16x4 ph = *(const f16x4*)(AH + (size_t)rowp*256 + lane*4);
  f16x4 pl = *(const f16x4*)(AL + (size_t)rowp*256 + lane*4);
  for (int s = 0; s < 16; ++s){
    int row  = __shfl(myrow, s, 64);
    int code = __shfl(mycode, s, 64);
    f16x4 h4 = ph, l4 = pl;
    if (s < 15){
      int rown = __shfl(myrow, s+1, 64);
      ph = *(const f16x4*)(AH + (size_t)rown*256 + lane*4);
      pl = *(const f16x4*)(AL + (size_t)rown*256 + lane*4);
    }
    if (code != prev){
      if (prev >= 0){
        float* dst = out4 + (((size_t)q << 10) + prev)*256 + lane*4;
        #pragma unroll
        for (int t = 0; t < 4; ++t) atomicAdd(dst + t, vs[t] * OMG_F);
      }
      if (!LAST){
        float4 wv = *(const float4*)&codebooks[(((size_t)q << 10) + code)*256 + lane*4];
        Wk[0] = wv.x; Wk[1] = wv.y; Wk[2] = wv.z; Wk[3] = wv.w;
      }
      vs[0] = vs[1] = vs[2] = vs[3] = 0.f;
      prev = code;
    }
    float p = 0.f;
    f16x4 nh, nl;
    #pragma unroll
    for (int t = 0; t < 4; ++t){
      float rj = (float)h4[t] + (float)l4[t] * LO_INV;
      vs[t] += rj;
      if (!LAST){
        float rn_ = rj - Wk[t];
        f16 hh = (f16)rn_;
        nh[t] = hh;
        nl[t] = (f16)((rn_ - (float)hh) * LO_SCALE);
        p += rn_ * rn_;
      }
    }
    if (!LAST){
      size_t base = (size_t)row * 256 + lane*4;
      *(f16x4*)(AH + base) = nh;
      *(f16x4*)(AL + base) = nl;
      #pragma unroll
      for (int o = 32; o > 0; o >>= 1) p += __shfl_down(p, o, 64);
      if (lane == 0) rnorm[row] = p;
    }
  }
  if (prev >= 0){
    float* dst = out4 + (((size_t)q << 10) + prev)*256 + lane*4;
    #pragma unroll
    for (int t = 0; t < 4; ++t) atomicAdd(dst + t, vs[t] * OMG_F);
  }
}

// ---------- epilogue: logits = data - (r7 - W7[c7]), loss ----------
__global__ __launch_bounds__(256) void logits_loss_kernel(
    const float* __restrict__ data, const f16* __restrict__ AH, const f16* __restrict__ AL,
    const float* __restrict__ out2q7, const float* __restrict__ W7,
    float* __restrict__ out0, float* __restrict__ out1)
{
  __shared__ float rs[32][257];
  int blk = blockIdx.x, b = blk >> 6, s0 = (blk & 63) * 32;
  int tid = threadIdx.x;
  int r0 = blk*32;
  int c2 = tid >> 3, k0 = (tid & 7) * 32;
  int grow = r0 + c2;
  int code = (int)out2q7[grow];
  const float* wrow = W7 + (size_t)code * 256 + k0;
  #pragma unroll
  for (int jc = 0; jc < 4; ++jc){
    size_t off = (size_t)grow * 256 + k0 + jc*8;
    f16x8 h8 = *(const f16x8*)(AH + off);
    f16x8 l8 = *(const f16x8*)(AL + off);
    float4 w0 = *(const float4*)(wrow + jc*8);
    float4 w1 = *(const float4*)(wrow + jc*8 + 4);
    float wv[8] = {w0.x,w0.y,w0.z,w0.w, w1.x,w1.y,w1.z,w1.w};
    #pragma unroll
    for (int j = 0; j < 8; ++j)
      rs[c2][k0 + jc*8 + j] = ((float)h8[j] + (float)l8[j] * LO_INV) - wv[j];
  }
  __syncthreads();
  int c = tid & 31, g = tid >> 5;
  const float* dptr = data + (size_t)b * 524288 + s0;
  float* optr = out0 + (size_t)b * 524288 + s0;
  float lsum = 0.f;
  #pragma unroll 8
  for (int dd = 0; dd < 32; ++dd){
    int d = g*32 + dd;
    float r = rs[c][d];
    lsum += r*r;
    optr[(size_t)d * 2048 + c] = dptr[(size_t)d * 2048 + c] - r;
  }
  #pragma unroll
  for (int o = 32; o > 0; o >>= 1) lsum += __shfl_down(lsum, o, 64);
  if ((tid & 63) == 0) atomicAdd(out1, lsum * (1.0f / 8388608.0f));
}

// ---------- final: new_W = new_m / clip(new_N) ----------
__global__ __launch_bounds__(256) void out5_kernel(const float* __restrict__ out4,
                                                   const float* __restrict__ out3,
                                                   float* __restrict__ out5){
  int e4 = blockIdx.x*256 + threadIdx.x;
  float Nn = fmaxf(out3[e4 >> 6], 1e-8f);
  float4 v = ((const float4*)out4)[e4];
  v.x /= Nn; v.y /= Nn; v.z /= Nn; v.w /= Nn;
  ((float4*)out5)[e4] = v;
}

extern "C" void kernel_launch(void* const* d_in, const int* in_sizes, int n_in,
                              void* d_out, int out_size, void* d_ws, size_t ws_size,
                              hipStream_t stream){
  float* out = (float*)d_out;

  // size-keyed input binding
  const float* data = nullptr; const float* codebooks = nullptr;
  const float* Ni = nullptr;   const float* mi = nullptr;
  for (int i = 0; i < n_in; ++i){
    if      (in_sizes[i] == 8388608) data = (const float*)d_in[i];
    else if (in_sizes[i] == 8192)    Ni   = (const float*)d_in[i];
    else if (in_sizes[i] == 2097152){
      if (!codebooks) codebooks = (const float*)d_in[i];
      else            mi        = (const float*)d_in[i];
    }
  }
  if (!data || !codebooks || !Ni || !mi){
    sentinel_kernel<<<1, 64, 0, stream>>>(out, 6666.0f);
    return;
  }

  // ws layout (bytes):
  // AH 16,777,216 | AL 16,777,216 | whl 8,388,608 | wnorm 32,768 | rnorm 131,072 |
  // blockhist 65,536 | rowlist 65,536 | keybuf 262,144 = 42,500,096
  const size_t ws_need = 42500096ull;
  if (ws_size < ws_need){
    sentinel_kernel<<<1, 64, 0, stream>>>(out, 7777.0f);
    return;
  }
  f16*   AH     = (f16*)d_ws;
  f16*   AL     = AH + 8388608;
  f16*   whl    = AL + 8388608;
  float* wnormb = (float*)(whl + 4194304);
  float* rnorm  = wnormb + 8192;
  unsigned short* blockhist = (unsigned short*)(rnorm + 32768);
  unsigned short* rowlist   = blockhist + 32768;
  u64*   keybuf = (u64*)(rowlist + 32768);

  // out offsets (fp32, reference return order)
  float* out0 = out;                  // logits  8388608
  float* out1 = out0 + 8388608;       // loss    1
  float* out2 = out1 + 1;             // indices 262144
  float* out3 = out2 + 262144;        // new_N   8192
  float* out4 = out3 + 8192;          // new_m   2097152
  float* out5 = out4 + 2097152;       // new_W   2097152

  hipMemsetAsync(out1, 0, sizeof(float), stream);
  hipMemsetAsync(keybuf, 0xFF, 262144, stream);

  wsplit_kernel<<<dim3(4096), 64, 0, stream>>>(codebooks, whl);
  rownorm_kernel<<<dim3(8192), 64, 0, stream>>>(codebooks, wnormb, 8192);
  init_kernel<<<dim3(1024), 256, 0, stream>>>(data, AH, AL, rnorm);
  out4init_kernel<<<dim3(2048), 256, 0, stream>>>(mi, out4);

  for (int q = 0; q < 8; ++q){
    float* out2q = out2 + (size_t)q * 32768;
    dist_kernel<<<dim3(256, 4), 256, 0, stream>>>(AH, AL, whl, wnormb, rnorm, keybuf, q);
    hist_kernel<<<dim3(32), 256, 0, stream>>>(keybuf, out2q, blockhist);
    scanscatter_kernel<<<dim3(32), 256, 0, stream>>>(blockhist, out2q, rowlist,
                                                     Ni, out3, q);
    if (q < 7)
      update_kernel<0><<<dim3(2048), 64, 0, stream>>>(AH, AL, rowlist, out2q,
                                                      codebooks, out4, rnorm, q);
    else
      update_kernel<1><<<dim3(2048), 64, 0, stream>>>(AH, AL, rowlist, out2q,
                                                      codebooks, out4, rnorm, q);
  }

  logits_loss_kernel<<<dim3(1024), 256, 0, stream>>>(data, AH, AL,
                                                     out2 + 7*32768,
                                                     codebooks + 7*262144,
                                                     out0, out1);
  out5_kernel<<<dim3(2048), 256, 0, stream>>>(out4, out3, out5);
}

// Round 14
// 883.547 us; speedup vs baseline: 2.0140x; 1.0188x over previous
//
#include <hip/hip_runtime.h>
#include <hip/hip_bf16.h>

// RQV residual VQ — MFMA dist (phase-staggered blocks + wn reg-hoist) + r13 tail.
// Inputs (fp32): data [16,256,2048], codebooks [8,1024,256], N_i [8,1024], m_i [8,1024,256]
// Outputs (fp32 concat): logits, loss, indices, new_N, new_m, new_W
// ws: AH/AL 2x16.78MB | whl 8.39MB | wnorm | rnorm | blockhist | rowlist | keybuf = 42,500,096 B

using f16   = _Float16;
using f16x4 = __attribute__((ext_vector_type(4))) _Float16;
using f16x8 = __attribute__((ext_vector_type(8))) _Float16;
using f32x4 = __attribute__((ext_vector_type(4))) float;
typedef unsigned long long u64;
typedef unsigned int u32;

#define GAMMA_F 0.99f
#define OMG_F   0.01f
#define LO_SCALE 1024.0f
#define LO_INV   (1.0f/1024.0f)

__device__ __forceinline__ void gload16(const void* g, void* l){
  __builtin_amdgcn_global_load_lds(
      (const __attribute__((address_space(1))) u32*)g,
      (__attribute__((address_space(3))) u32*)l, 16, 0, 0);
}

__global__ void sentinel_kernel(float* out, float v){
  if (threadIdx.x == 0 && blockIdx.x == 0) out[0] = v;
}

// ---------- codebook row norms ----------
__global__ __launch_bounds__(64) void rownorm_kernel(const float* __restrict__ X,
                                                     float* __restrict__ out, int rows){
  int r = blockIdx.x;
  if (r >= rows) return;
  int l = threadIdx.x;
  const float* x = X + (size_t)r * 256;
  float s = 0.f;
  #pragma unroll
  for (int i = 0; i < 4; i++){ float v = x[l + i*64]; s += v*v; }
  #pragma unroll
  for (int o = 32; o > 0; o >>= 1) s += __shfl_down(s, o, 64);
  if (l == 0) out[r] = s;
}

// ---------- codebook split into MFMA B-fragment order (verified) ----------
__global__ __launch_bounds__(64) void wsplit_kernel(const float* __restrict__ W,
                                                    f16* __restrict__ frag){
  int blk = blockIdx.x;                 // (q*64+ct)*8+kf
  int lane = threadIdx.x;
  int code = (blk >> 3 << 4) + (lane & 15);
  int k0   = (blk & 7)*32 + (lane >> 4)*8;
  const float* src = W + (size_t)code * 256 + k0;
  float4 a = *(const float4*)(src);
  float4 b = *(const float4*)(src + 4);
  float x[8] = {a.x,a.y,a.z,a.w, b.x,b.y,b.z,b.w};
  f16x8 h8, l8;
  #pragma unroll
  for (int i = 0; i < 8; i++){
    f16 h = (f16)x[i];
    h8[i] = h;
    l8[i] = (f16)((x[i] - (float)h) * LO_SCALE);
  }
  f16* dst = frag + (size_t)blk * 1024 + lane*8;
  *(f16x8*)dst         = h8;
  *(f16x8*)(dst + 512) = l8;
}

// ---------- init: data -> ROW-MAJOR fp16 hi/lo planes + rownorm ----------
__global__ __launch_bounds__(256) void init_kernel(const float* __restrict__ data,
                                                   f16* __restrict__ AH, f16* __restrict__ AL,
                                                   float* __restrict__ rnorm){
  __shared__ float rs[32][257];
  __shared__ float nrmp[32][8];
  int blk = blockIdx.x, b = blk >> 6, s0 = (blk & 63) * 32;
  int tid = threadIdx.x, c = tid & 31, g = tid >> 5;
  const float* dptr = data + (size_t)b * 524288 + s0;
  float np_ = 0.f;
  #pragma unroll 8
  for (int dd = 0; dd < 32; ++dd){
    int d = g*32 + dd;
    float x = dptr[(size_t)d * 2048 + c];
    rs[c][d] = x;
    np_ += x*x;
  }
  nrmp[c][g] = np_;
  __syncthreads();
  if (tid < 32){
    float s = 0.f;
    #pragma unroll
    for (int gg = 0; gg < 8; ++gg) s += nrmp[tid][gg];
    rnorm[blk*32 + tid] = s;
  }
  int r0 = blk*32;
  int c2 = tid >> 3, k0 = (tid & 7) * 32;
  #pragma unroll
  for (int jc = 0; jc < 4; ++jc){
    f16x8 h8, l8;
    #pragma unroll
    for (int j = 0; j < 8; ++j){
      float x = rs[c2][k0 + jc*8 + j];
      f16 h = (f16)x;
      h8[j] = h;
      l8[j] = (f16)((x - (float)h) * LO_SCALE);
    }
    size_t off = (size_t)(r0 + c2) * 256 + k0 + jc*8;
    *(f16x8*)(AH + off) = h8;
    *(f16x8*)(AL + off) = l8;
  }
}

// ---------- out4 = mi * gamma ----------
__global__ __launch_bounds__(256) void out4init_kernel(const float* __restrict__ mi,
                                                       float* __restrict__ out4){
  int e4 = blockIdx.x*256 + threadIdx.x;
  float4 v = ((const float4*)mi)[e4];
  v.x *= GAMMA_F; v.y *= GAMMA_F; v.z *= GAMMA_F; v.w *= GAMMA_F;
  ((float4*)out4)[e4] = v;
}

// ---------- dist: staggered tile order per block, 3-ring gload_lds, counted vmcnt ----------
__global__ __launch_bounds__(256, 2) void dist_kernel(
    const f16* __restrict__ AH, const f16* __restrict__ AL,
    const f16* __restrict__ whl, const float* __restrict__ wnorm,
    const float* __restrict__ rnorm, u64* __restrict__ keybuf, int q)
{
  __shared__ f16 Bs[3][8192];          // 16-code tile (bh+bl) per buffer: 16 KB x 3
  const int tid = threadIdx.x;
  const int lane = tid & 63;
  const int w = tid >> 6;
  const int rb = blockIdx.x, cs = blockIdx.y;
  const int rlo = lane & 15, kg = lane >> 4;
  const int T0 = rb*8 + w*2;
  const int off = (rb & 3) * 4;        // phase-stagger: co-resident blocks desync

  // A fragments (32 rows, hi/lo) from row-major planes — coalesced
  f16x8 aH[2][8], aL[2][8];
  #pragma unroll
  for (int rt = 0; rt < 2; ++rt)
    #pragma unroll
    for (int kf = 0; kf < 8; ++kf){
      size_t offb = (size_t)((T0+rt)*16 + rlo) * 256 + kf*32 + kg*8;
      aH[rt][kf] = *(const f16x8*)(AH + offb);
      aL[rt][kf] = *(const f16x8*)(AL + offb);
    }
  float rn[2][4];
  #pragma unroll
  for (int rt = 0; rt < 2; ++rt)
    #pragma unroll
    for (int i = 0; i < 4; ++i)
      rn[rt][i] = rnorm[(T0+rt)*16 + kg*4 + i];

  const f16* wb = whl + (size_t)q * 524288;
  const float* wn = wnorm + (q << 10);
  const int ct0 = cs * 16;             // 16 tiles (cts) per cs-block

  // hoist wn: wnr[j] = wn value for iteration j's tile (static-indexed under unroll)
  float wnr[16];
  #pragma unroll
  for (int j = 0; j < 16; ++j)
    wnr[j] = wn[((ct0 + ((j + off) & 15)) << 4) + rlo];

  float bestv[8]; int besti[8];
  #pragma unroll
  for (int r8_ = 0; r8_ < 8; ++r8_){ bestv[r8_] = 3.4e38f; besti[r8_] = 0; }

  // wave-quarter staging of one 16 KB tile = 4 gload16 per wave
  auto issue = [&](int buf, int ct_){
    const f16* src = wb + (size_t)ct_ * 8192 + w*2048 + lane*8;
    f16* dst = &Bs[buf][0] + w*2048;
    #pragma unroll
    for (int j = 0; j < 4; ++j)
      gload16(src + j*512, dst + j*512);
  };

  // prologue: tiles for iterations 0,1 in flight (8 vmem ops/wave)
  issue(0, ct0 + ((0 + off) & 15));
  issue(1, ct0 + ((1 + off) & 15));

  #pragma unroll
  for (int it = 0; it < 16; ++it){
    // counted wait: iteration `it`'s tile landed; it+1's 4 loads may stay in flight
    if (it < 15) asm volatile("s_waitcnt vmcnt(4)" ::: "memory");
    else         asm volatile("s_waitcnt vmcnt(0)" ::: "memory");
    __builtin_amdgcn_sched_barrier(0);
    __builtin_amdgcn_s_barrier();      // tile `it` visible; tile `it-1` compute done
    __builtin_amdgcn_sched_barrier(0);
    if (it < 14) issue((it + 2) % 3, ct0 + ((it + 2 + off) & 15));

    const f16* bb = &Bs[it % 3][0];
    f32x4 hh[2], cr[2];
    #pragma unroll
    for (int rt = 0; rt < 2; ++rt){ hh[rt] = (f32x4)0.0f; cr[rt] = (f32x4)0.0f; }
    __builtin_amdgcn_s_setprio(1);
    #pragma unroll
    for (int kf = 0; kf < 8; ++kf){
      f16x8 bh = *(const f16x8*)(bb + kf*1024 + lane*8);
      f16x8 bl = *(const f16x8*)(bb + kf*1024 + 512 + lane*8);
      hh[0] = __builtin_amdgcn_mfma_f32_16x16x32_f16(aH[0][kf], bh, hh[0], 0,0,0);
      cr[0] = __builtin_amdgcn_mfma_f32_16x16x32_f16(aH[0][kf], bl, cr[0], 0,0,0);
      cr[0] = __builtin_amdgcn_mfma_f32_16x16x32_f16(aL[0][kf], bh, cr[0], 0,0,0);
      hh[1] = __builtin_amdgcn_mfma_f32_16x16x32_f16(aH[1][kf], bh, hh[1], 0,0,0);
      cr[1] = __builtin_amdgcn_mfma_f32_16x16x32_f16(aH[1][kf], bl, cr[1], 0,0,0);
      cr[1] = __builtin_amdgcn_mfma_f32_16x16x32_f16(aL[1][kf], bh, cr[1], 0,0,0);
    }
    __builtin_amdgcn_s_setprio(0);
    int ct = ct0 + ((it + off) & 15);
    int code = (ct << 4) + rlo;
    float wnc = wnr[it];
    #pragma unroll
    for (int rt = 0; rt < 2; ++rt)
      #pragma unroll
      for (int i = 0; i < 4; ++i){
        float dot = hh[rt][i] + cr[rt][i] * LO_INV;
        float d2 = (rn[rt][i] + wnc) - 2.0f * dot;
        int r8_ = rt*4 + i;
        if (d2 < bestv[r8_] || (d2 == bestv[r8_] && code < besti[r8_])){
          bestv[r8_] = d2; besti[r8_] = code;
        }
      }
  }

  // reduce across the 16 code-lanes (first-min, lowest index)
  #pragma unroll
  for (int o = 1; o <= 8; o <<= 1){
    #pragma unroll
    for (int r8_ = 0; r8_ < 8; ++r8_){
      float ov = __shfl_xor(bestv[r8_], o, 16);
      int   oi = __shfl_xor(besti[r8_], o, 16);
      if (ov < bestv[r8_] || (ov == bestv[r8_] && oi < besti[r8_])){
        bestv[r8_] = ov; besti[r8_] = oi;
      }
    }
  }
  if (rlo == 0){
    #pragma unroll
    for (int r8_ = 0; r8_ < 8; ++r8_){
      int rt = r8_ >> 2, i = r8_ & 3;
      int grow = (T0 + rt)*16 + kg*4 + i;
      unsigned fb = __float_as_uint(bestv[r8_]);
      fb = (fb & 0x80000000u) ? ~fb : (fb | 0x80000000u);   // monotone sortable
      u64 key = ((u64)fb << 32) | (unsigned)besti[r8_];
      atomicMin(keybuf + grow, key);
    }
  }
}

// ---------- hist: extract codes from keys, per-block histogram, reset keybuf ----------
__global__ __launch_bounds__(256) void hist_kernel(u64* __restrict__ keybuf,
                                                   float* __restrict__ out2q,
                                                   unsigned short* __restrict__ blockhist){
  __shared__ int h[1024];
  int tid = threadIdx.x, b = blockIdx.x;
  #pragma unroll
  for (int i = 0; i < 4; ++i) h[tid + 256*i] = 0;
  __syncthreads();
  #pragma unroll
  for (int j = 0; j < 4; ++j){
    int row = b*1024 + tid + 256*j;
    u64 k = keybuf[row];
    keybuf[row] = ~0ull;               // reset for next stage
    int c = (int)(k & 0xFFFF);
    out2q[row] = (float)c;
    atomicAdd(&h[c], 1);
  }
  __syncthreads();
  #pragma unroll
  for (int i = 0; i < 4; ++i)
    blockhist[b*1024 + tid + 256*i] = (unsigned short)h[tid + 256*i];
}

// ---------- fused scan + scatter (32 blocks, redundant scan) + new_N ----------
__global__ __launch_bounds__(256) void scanscatter_kernel(
    const unsigned short* __restrict__ blockhist, const float* __restrict__ out2q,
    unsigned short* __restrict__ rowlist, const float* __restrict__ Ni,
    float* __restrict__ out3, int q)
{
  __shared__ int wtot[4];
  __shared__ int cur[1024];
  int tid = threadIdx.x, b = blockIdx.x, lane = tid & 63, w = tid >> 6;
  const ushort4* bh4 = (const ushort4*)blockhist;
  int tot[4] = {0,0,0,0}, pre[4] = {0,0,0,0};
  for (int bb = 0; bb < 32; ++bb){
    ushort4 h = bh4[bb*256 + tid];
    if (bb < b){ pre[0]+=h.x; pre[1]+=h.y; pre[2]+=h.z; pre[3]+=h.w; }
    tot[0]+=h.x; tot[1]+=h.y; tot[2]+=h.z; tot[3]+=h.w;
  }
  int s = tot[0]+tot[1]+tot[2]+tot[3];
  int v = s;
  #pragma unroll
  for (int d = 1; d < 64; d <<= 1){
    int o = __shfl_up(v, d, 64);
    if (lane >= d) v += o;
  }
  if (lane == 63) wtot[w] = v;
  __syncthreads();
  int woff = 0;
  #pragma unroll
  for (int ww = 0; ww < 4; ++ww) if (ww < w) woff += wtot[ww];
  int base = woff + v - s;             // global exclusive prefix for code 4*tid
  if (b == 0){
    const int qb = q << 10;
    out3[qb + 4*tid+0] = Ni[qb + 4*tid+0]*GAMMA_F + (float)tot[0]*OMG_F;
    out3[qb + 4*tid+1] = Ni[qb + 4*tid+1]*GAMMA_F + (float)tot[1]*OMG_F;
    out3[qb + 4*tid+2] = Ni[qb + 4*tid+2]*GAMMA_F + (float)tot[2]*OMG_F;
    out3[qb + 4*tid+3] = Ni[qb + 4*tid+3]*GAMMA_F + (float)tot[3]*OMG_F;
  }
  cur[4*tid+0] = base + pre[0];
  cur[4*tid+1] = base + tot[0] + pre[1];
  cur[4*tid+2] = base + tot[0]+tot[1] + pre[2];
  cur[4*tid+3] = base + tot[0]+tot[1]+tot[2] + pre[3];
  __syncthreads();
  #pragma unroll
  for (int j = 0; j < 4; ++j){
    int row = b*1024 + tid + 256*j;
    int c = (int)out2q[row];
    int pos = atomicAdd(&cur[c], 1);
    rowlist[pos] = (unsigned short)row;
  }
}

// ---------- update: 2048 1-wave blocks, 16 slots, 2-deep prefetch ----------
// LAST=1 (q=7): skip residual writeback + rnorm (logits kernel applies final subtract).
template<int LAST>
__global__ __launch_bounds__(64) void update_kernel(
    f16* __restrict__ AH, f16* __restrict__ AL,
    const unsigned short* __restrict__ rowlist, const float* __restrict__ out2q,
    const float* __restrict__ codebooks, float* __restrict__ out4,
    float* __restrict__ rnorm, int q)
{
  const int lane = threadIdx.x;
  const int s0 = blockIdx.x * 16;
  int myrow = 0, mycode = 0;
  if (lane < 16){
    myrow = rowlist[s0 + lane];
    mycode = (int)out2q[myrow];
  }
  float vs[4] = {0.f, 0.f, 0.f, 0.f};
  float Wk[4] = {0.f, 0.f, 0.f, 0.f};
  int prev = -1;
  int rowp = __shfl(myrow, 0, 64);
  f16x4 ph = *(const f16x4*)(AH + (size_t)rowp*256 + lane*4);
  f16x4 pl = *(const f16x4*)(AL + (size_t)rowp*256 + lane*4);
  for (int s = 0; s < 16; ++s){
    int row  = __shfl(myrow, s, 64);
    int code = __shfl(mycode, s, 64);
    f16x4 h4 = ph, l4 = pl;
    if (s < 15){
      int rown = __shfl(myrow, s+1, 64);
      ph = *(const f16x4*)(AH + (size_t)rown*256 + lane*4);
      pl = *(const f16x4*)(AL + (size_t)rown*256 + lane*4);
    }
    if (code != prev){
      if (prev >= 0){
        float* dst = out4 + (((size_t)q << 10) + prev)*256 + lane*4;
        #pragma unroll
        for (int t = 0; t < 4; ++t) atomicAdd(dst + t, vs[t] * OMG_F);
      }
      if (!LAST){
        float4 wv = *(const float4*)&codebooks[(((size_t)q << 10) + code)*256 + lane*4];
        Wk[0] = wv.x; Wk[1] = wv.y; Wk[2] = wv.z; Wk[3] = wv.w;
      }
      vs[0] = vs[1] = vs[2] = vs[3] = 0.f;
      prev = code;
    }
    float p = 0.f;
    f16x4 nh, nl;
    #pragma unroll
    for (int t = 0; t < 4; ++t){
      float rj = (float)h4[t] + (float)l4[t] * LO_INV;
      vs[t] += rj;
      if (!LAST){
        float rn_ = rj - Wk[t];
        f16 hh = (f16)rn_;
        nh[t] = hh;
        nl[t] = (f16)((rn_ - (float)hh) * LO_SCALE);
        p += rn_ * rn_;
      }
    }
    if (!LAST){
      size_t base = (size_t)row * 256 + lane*4;
      *(f16x4*)(AH + base) = nh;
      *(f16x4*)(AL + base) = nl;
      #pragma unroll
      for (int o = 32; o > 0; o >>= 1) p += __shfl_down(p, o, 64);
      if (lane == 0) rnorm[row] = p;
    }
  }
  if (prev >= 0){
    float* dst = out4 + (((size_t)q << 10) + prev)*256 + lane*4;
    #pragma unroll
    for (int t = 0; t < 4; ++t) atomicAdd(dst + t, vs[t] * OMG_F);
  }
}

// ---------- epilogue: logits = data - (r7 - W7[c7]), loss ----------
__global__ __launch_bounds__(256) void logits_loss_kernel(
    const float* __restrict__ data, const f16* __restrict__ AH, const f16* __restrict__ AL,
    const float* __restrict__ out2q7, const float* __restrict__ W7,
    float* __restrict__ out0, float* __restrict__ out1)
{
  __shared__ float rs[32][257];
  int blk = blockIdx.x, b = blk >> 6, s0 = (blk & 63) * 32;
  int tid = threadIdx.x;
  int r0 = blk*32;
  int c2 = tid >> 3, k0 = (tid & 7) * 32;
  int grow = r0 + c2;
  int code = (int)out2q7[grow];
  const float* wrow = W7 + (size_t)code * 256 + k0;
  #pragma unroll
  for (int jc = 0; jc < 4; ++jc){
    size_t off = (size_t)grow * 256 + k0 + jc*8;
    f16x8 h8 = *(const f16x8*)(AH + off);
    f16x8 l8 = *(const f16x8*)(AL + off);
    float4 w0 = *(const float4*)(wrow + jc*8);
    float4 w1 = *(const float4*)(wrow + jc*8 + 4);
    float wv[8] = {w0.x,w0.y,w0.z,w0.w, w1.x,w1.y,w1.z,w1.w};
    #pragma unroll
    for (int j = 0; j < 8; ++j)
      rs[c2][k0 + jc*8 + j] = ((float)h8[j] + (float)l8[j] * LO_INV) - wv[j];
  }
  __syncthreads();
  int c = tid & 31, g = tid >> 5;
  const float* dptr = data + (size_t)b * 524288 + s0;
  float* optr = out0 + (size_t)b * 524288 + s0;
  float lsum = 0.f;
  #pragma unroll 8
  for (int dd = 0; dd < 32; ++dd){
    int d = g*32 + dd;
    float r = rs[c][d];
    lsum += r*r;
    optr[(size_t)d * 2048 + c] = dptr[(size_t)d * 2048 + c] - r;
  }
  #pragma unroll
  for (int o = 32; o > 0; o >>= 1) lsum += __shfl_down(lsum, o, 64);
  if ((tid & 63) == 0) atomicAdd(out1, lsum * (1.0f / 8388608.0f));
}

// ---------- final: new_W = new_m / clip(new_N) ----------
__global__ __launch_bounds__(256) void out5_kernel(const float* __restrict__ out4,
                                                   const float* __restrict__ out3,
                                                   float* __restrict__ out5){
  int e4 = blockIdx.x*256 + threadIdx.x;
  float Nn = fmaxf(out3[e4 >> 6], 1e-8f);
  float4 v = ((const float4*)out4)[e4];
  v.x /= Nn; v.y /= Nn; v.z /= Nn; v.w /= Nn;
  ((float4*)out5)[e4] = v;
}

extern "C" void kernel_launch(void* const* d_in, const int* in_sizes, int n_in,
                              void* d_out, int out_size, void* d_ws, size_t ws_size,
                              hipStream_t stream){
  float* out = (float*)d_out;

  // size-keyed input binding
  const float* data = nullptr; const float* codebooks = nullptr;
  const float* Ni = nullptr;   const float* mi = nullptr;
  for (int i = 0; i < n_in; ++i){
    if      (in_sizes[i] == 8388608) data = (const float*)d_in[i];
    else if (in_sizes[i] == 8192)    Ni   = (const float*)d_in[i];
    else if (in_sizes[i] == 2097152){
      if (!codebooks) codebooks = (const float*)d_in[i];
      else            mi        = (const float*)d_in[i];
    }
  }
  if (!data || !codebooks || !Ni || !mi){
    sentinel_kernel<<<1, 64, 0, stream>>>(out, 6666.0f);
    return;
  }

  // ws layout (bytes):
  // AH 16,777,216 | AL 16,777,216 | whl 8,388,608 | wnorm 32,768 | rnorm 131,072 |
  // blockhist 65,536 | rowlist 65,536 | keybuf 262,144 = 42,500,096
  const size_t ws_need = 42500096ull;
  if (ws_size < ws_need){
    sentinel_kernel<<<1, 64, 0, stream>>>(out, 7777.0f);
    return;
  }
  f16*   AH     = (f16*)d_ws;
  f16*   AL     = AH + 8388608;
  f16*   whl    = AL + 8388608;
  float* wnormb = (float*)(whl + 4194304);
  float* rnorm  = wnormb + 8192;
  unsigned short* blockhist = (unsigned short*)(rnorm + 32768);
  unsigned short* rowlist   = blockhist + 32768;
  u64*   keybuf = (u64*)(rowlist + 32768);

  // out offsets (fp32, reference return order)
  float* out0 = out;                  // logits  8388608
  float* out1 = out0 + 8388608;       // loss    1
  float* out2 = out1 + 1;             // indices 262144
  float* out3 = out2 + 262144;        // new_N   8192
  float* out4 = out3 + 8192;          // new_m   2097152
  float* out5 = out4 + 2097152;       // new_W   2097152

  hipMemsetAsync(out1, 0, sizeof(float), stream);
  hipMemsetAsync(keybuf, 0xFF, 262144, stream);

  wsplit_kernel<<<dim3(4096), 64, 0, stream>>>(codebooks, whl);
  rownorm_kernel<<<dim3(8192), 64, 0, stream>>>(codebooks, wnormb, 8192);
  init_kernel<<<dim3(1024), 256, 0, stream>>>(data, AH, AL, rnorm);
  out4init_kernel<<<dim3(2048), 256, 0, stream>>>(mi, out4);

  for (int q = 0; q < 8; ++q){
    float* out2q = out2 + (size_t)q * 32768;
    dist_kernel<<<dim3(256, 4), 256, 0, stream>>>(AH, AL, whl, wnormb, rnorm, keybuf, q);
    hist_kernel<<<dim3(32), 256, 0, stream>>>(keybuf, out2q, blockhist);
    scanscatter_kernel<<<dim3(32), 256, 0, stream>>>(blockhist, out2q, rowlist,
                                                     Ni, out3, q);
    if (q < 7)
      update_kernel<0><<<dim3(2048), 64, 0, stream>>>(AH, AL, rowlist, out2q,
                                                      codebooks, out4, rnorm, q);
    else
      update_kernel<1><<<dim3(2048), 64, 0, stream>>>(AH, AL, rowlist, out2q,
                                                      codebooks, out4, rnorm, q);
  }

  logits_loss_kernel<<<dim3(1024), 256, 0, stream>>>(data, AH, AL,
                                                     out2 + 7*32768,
                                                     codebooks + 7*262144,
                                                     out0, out1);
  out5_kernel<<<dim3(2048), 256, 0, stream>>>(out4, out3, out5);
}

// Round 15
// 874.642 us; speedup vs baseline: 2.0345x; 1.0102x over previous
//
#include <hip/hip_runtime.h>
#include <hip/hip_bf16.h>

// RQV residual VQ — r14 dist + preloaded update (latency-flattened tail).
// Inputs (fp32): data [16,256,2048], codebooks [8,1024,256], N_i [8,1024], m_i [8,1024,256]
// Outputs (fp32 concat): logits, loss, indices, new_N, new_m, new_W
// ws: AH/AL 2x16.78MB | whl 8.39MB | wnorm | rnorm | blockhist | rowlist(u32) | keybuf
//     = 42,565,632 B (<= 43,122,688 proven available in r8)

using f16   = _Float16;
using f16x4 = __attribute__((ext_vector_type(4))) _Float16;
using f16x8 = __attribute__((ext_vector_type(8))) _Float16;
using f32x4 = __attribute__((ext_vector_type(4))) float;
typedef unsigned long long u64;
typedef unsigned int u32;

#define GAMMA_F 0.99f
#define OMG_F   0.01f
#define LO_SCALE 1024.0f
#define LO_INV   (1.0f/1024.0f)

__device__ __forceinline__ void gload16(const void* g, void* l){
  __builtin_amdgcn_global_load_lds(
      (const __attribute__((address_space(1))) u32*)g,
      (__attribute__((address_space(3))) u32*)l, 16, 0, 0);
}

__global__ void sentinel_kernel(float* out, float v){
  if (threadIdx.x == 0 && blockIdx.x == 0) out[0] = v;
}

// ---------- codebook row norms ----------
__global__ __launch_bounds__(64) void rownorm_kernel(const float* __restrict__ X,
                                                     float* __restrict__ out, int rows){
  int r = blockIdx.x;
  if (r >= rows) return;
  int l = threadIdx.x;
  const float* x = X + (size_t)r * 256;
  float s = 0.f;
  #pragma unroll
  for (int i = 0; i < 4; i++){ float v = x[l + i*64]; s += v*v; }
  #pragma unroll
  for (int o = 32; o > 0; o >>= 1) s += __shfl_down(s, o, 64);
  if (l == 0) out[r] = s;
}

// ---------- codebook split into MFMA B-fragment order (verified) ----------
__global__ __launch_bounds__(64) void wsplit_kernel(const float* __restrict__ W,
                                                    f16* __restrict__ frag){
  int blk = blockIdx.x;                 // (q*64+ct)*8+kf
  int lane = threadIdx.x;
  int code = (blk >> 3 << 4) + (lane & 15);
  int k0   = (blk & 7)*32 + (lane >> 4)*8;
  const float* src = W + (size_t)code * 256 + k0;
  float4 a = *(const float4*)(src);
  float4 b = *(const float4*)(src + 4);
  float x[8] = {a.x,a.y,a.z,a.w, b.x,b.y,b.z,b.w};
  f16x8 h8, l8;
  #pragma unroll
  for (int i = 0; i < 8; i++){
    f16 h = (f16)x[i];
    h8[i] = h;
    l8[i] = (f16)((x[i] - (float)h) * LO_SCALE);
  }
  f16* dst = frag + (size_t)blk * 1024 + lane*8;
  *(f16x8*)dst         = h8;
  *(f16x8*)(dst + 512) = l8;
}

// ---------- init: data -> ROW-MAJOR fp16 hi/lo planes + rownorm ----------
__global__ __launch_bounds__(256) void init_kernel(const float* __restrict__ data,
                                                   f16* __restrict__ AH, f16* __restrict__ AL,
                                                   float* __restrict__ rnorm){
  __shared__ float rs[32][257];
  __shared__ float nrmp[32][8];
  int blk = blockIdx.x, b = blk >> 6, s0 = (blk & 63) * 32;
  int tid = threadIdx.x, c = tid & 31, g = tid >> 5;
  const float* dptr = data + (size_t)b * 524288 + s0;
  float np_ = 0.f;
  #pragma unroll 8
  for (int dd = 0; dd < 32; ++dd){
    int d = g*32 + dd;
    float x = dptr[(size_t)d * 2048 + c];
    rs[c][d] = x;
    np_ += x*x;
  }
  nrmp[c][g] = np_;
  __syncthreads();
  if (tid < 32){
    float s = 0.f;
    #pragma unroll
    for (int gg = 0; gg < 8; ++gg) s += nrmp[tid][gg];
    rnorm[blk*32 + tid] = s;
  }
  int r0 = blk*32;
  int c2 = tid >> 3, k0 = (tid & 7) * 32;
  #pragma unroll
  for (int jc = 0; jc < 4; ++jc){
    f16x8 h8, l8;
    #pragma unroll
    for (int j = 0; j < 8; ++j){
      float x = rs[c2][k0 + jc*8 + j];
      f16 h = (f16)x;
      h8[j] = h;
      l8[j] = (f16)((x - (float)h) * LO_SCALE);
    }
    size_t off = (size_t)(r0 + c2) * 256 + k0 + jc*8;
    *(f16x8*)(AH + off) = h8;
    *(f16x8*)(AL + off) = l8;
  }
}

// ---------- out4 = mi * gamma ----------
__global__ __launch_bounds__(256) void out4init_kernel(const float* __restrict__ mi,
                                                       float* __restrict__ out4){
  int e4 = blockIdx.x*256 + threadIdx.x;
  float4 v = ((const float4*)mi)[e4];
  v.x *= GAMMA_F; v.y *= GAMMA_F; v.z *= GAMMA_F; v.w *= GAMMA_F;
  ((float4*)out4)[e4] = v;
}

// ---------- dist: staggered tile order, 3-ring gload_lds, counted vmcnt (r14) ----------
__global__ __launch_bounds__(256, 2) void dist_kernel(
    const f16* __restrict__ AH, const f16* __restrict__ AL,
    const f16* __restrict__ whl, const float* __restrict__ wnorm,
    const float* __restrict__ rnorm, u64* __restrict__ keybuf, int q)
{
  __shared__ f16 Bs[3][8192];          // 16-code tile (bh+bl) per buffer: 16 KB x 3
  const int tid = threadIdx.x;
  const int lane = tid & 63;
  const int w = tid >> 6;
  const int rb = blockIdx.x, cs = blockIdx.y;
  const int rlo = lane & 15, kg = lane >> 4;
  const int T0 = rb*8 + w*2;
  const int off = (rb & 3) * 4;        // phase-stagger: co-resident blocks desync

  f16x8 aH[2][8], aL[2][8];
  #pragma unroll
  for (int rt = 0; rt < 2; ++rt)
    #pragma unroll
    for (int kf = 0; kf < 8; ++kf){
      size_t offb = (size_t)((T0+rt)*16 + rlo) * 256 + kf*32 + kg*8;
      aH[rt][kf] = *(const f16x8*)(AH + offb);
      aL[rt][kf] = *(const f16x8*)(AL + offb);
    }
  float rn[2][4];
  #pragma unroll
  for (int rt = 0; rt < 2; ++rt)
    #pragma unroll
    for (int i = 0; i < 4; ++i)
      rn[rt][i] = rnorm[(T0+rt)*16 + kg*4 + i];

  const f16* wb = whl + (size_t)q * 524288;
  const float* wn = wnorm + (q << 10);
  const int ct0 = cs * 16;

  float wnr[16];
  #pragma unroll
  for (int j = 0; j < 16; ++j)
    wnr[j] = wn[((ct0 + ((j + off) & 15)) << 4) + rlo];

  float bestv[8]; int besti[8];
  #pragma unroll
  for (int r8_ = 0; r8_ < 8; ++r8_){ bestv[r8_] = 3.4e38f; besti[r8_] = 0; }

  auto issue = [&](int buf, int ct_){
    const f16* src = wb + (size_t)ct_ * 8192 + w*2048 + lane*8;
    f16* dst = &Bs[buf][0] + w*2048;
    #pragma unroll
    for (int j = 0; j < 4; ++j)
      gload16(src + j*512, dst + j*512);
  };

  issue(0, ct0 + ((0 + off) & 15));
  issue(1, ct0 + ((1 + off) & 15));

  #pragma unroll
  for (int it = 0; it < 16; ++it){
    if (it < 15) asm volatile("s_waitcnt vmcnt(4)" ::: "memory");
    else         asm volatile("s_waitcnt vmcnt(0)" ::: "memory");
    __builtin_amdgcn_sched_barrier(0);
    __builtin_amdgcn_s_barrier();
    __builtin_amdgcn_sched_barrier(0);
    if (it < 14) issue((it + 2) % 3, ct0 + ((it + 2 + off) & 15));

    const f16* bb = &Bs[it % 3][0];
    f32x4 hh[2], cr[2];
    #pragma unroll
    for (int rt = 0; rt < 2; ++rt){ hh[rt] = (f32x4)0.0f; cr[rt] = (f32x4)0.0f; }
    __builtin_amdgcn_s_setprio(1);
    #pragma unroll
    for (int kf = 0; kf < 8; ++kf){
      f16x8 bh = *(const f16x8*)(bb + kf*1024 + lane*8);
      f16x8 bl = *(const f16x8*)(bb + kf*1024 + 512 + lane*8);
      hh[0] = __builtin_amdgcn_mfma_f32_16x16x32_f16(aH[0][kf], bh, hh[0], 0,0,0);
      cr[0] = __builtin_amdgcn_mfma_f32_16x16x32_f16(aH[0][kf], bl, cr[0], 0,0,0);
      cr[0] = __builtin_amdgcn_mfma_f32_16x16x32_f16(aL[0][kf], bh, cr[0], 0,0,0);
      hh[1] = __builtin_amdgcn_mfma_f32_16x16x32_f16(aH[1][kf], bh, hh[1], 0,0,0);
      cr[1] = __builtin_amdgcn_mfma_f32_16x16x32_f16(aH[1][kf], bl, cr[1], 0,0,0);
      cr[1] = __builtin_amdgcn_mfma_f32_16x16x32_f16(aL[1][kf], bh, cr[1], 0,0,0);
    }
    __builtin_amdgcn_s_setprio(0);
    int ct = ct0 + ((it + off) & 15);
    int code = (ct << 4) + rlo;
    float wnc = wnr[it];
    #pragma unroll
    for (int rt = 0; rt < 2; ++rt)
      #pragma unroll
      for (int i = 0; i < 4; ++i){
        float dot = hh[rt][i] + cr[rt][i] * LO_INV;
        float d2 = (rn[rt][i] + wnc) - 2.0f * dot;
        int r8_ = rt*4 + i;
        if (d2 < bestv[r8_] || (d2 == bestv[r8_] && code < besti[r8_])){
          bestv[r8_] = d2; besti[r8_] = code;
        }
      }
  }

  #pragma unroll
  for (int o = 1; o <= 8; o <<= 1){
    #pragma unroll
    for (int r8_ = 0; r8_ < 8; ++r8_){
      float ov = __shfl_xor(bestv[r8_], o, 16);
      int   oi = __shfl_xor(besti[r8_], o, 16);
      if (ov < bestv[r8_] || (ov == bestv[r8_] && oi < besti[r8_])){
        bestv[r8_] = ov; besti[r8_] = oi;
      }
    }
  }
  if (rlo == 0){
    #pragma unroll
    for (int r8_ = 0; r8_ < 8; ++r8_){
      int rt = r8_ >> 2, i = r8_ & 3;
      int grow = (T0 + rt)*16 + kg*4 + i;
      unsigned fb = __float_as_uint(bestv[r8_]);
      fb = (fb & 0x80000000u) ? ~fb : (fb | 0x80000000u);
      u64 key = ((u64)fb << 32) | (unsigned)besti[r8_];
      atomicMin(keybuf + grow, key);
    }
  }
}

// ---------- hist: extract codes from keys, per-block histogram, reset keybuf ----------
__global__ __launch_bounds__(256) void hist_kernel(u64* __restrict__ keybuf,
                                                   float* __restrict__ out2q,
                                                   unsigned short* __restrict__ blockhist){
  __shared__ int h[1024];
  int tid = threadIdx.x, b = blockIdx.x;
  #pragma unroll
  for (int i = 0; i < 4; ++i) h[tid + 256*i] = 0;
  __syncthreads();
  #pragma unroll
  for (int j = 0; j < 4; ++j){
    int row = b*1024 + tid + 256*j;
    u64 k = keybuf[row];
    keybuf[row] = ~0ull;
    int c = (int)(k & 0xFFFF);
    out2q[row] = (float)c;
    atomicAdd(&h[c], 1);
  }
  __syncthreads();
  #pragma unroll
  for (int i = 0; i < 4; ++i)
    blockhist[b*1024 + tid + 256*i] = (unsigned short)h[tid + 256*i];
}

// ---------- fused scan + scatter; rowlist packs row | code<<16 ----------
__global__ __launch_bounds__(256) void scanscatter_kernel(
    const unsigned short* __restrict__ blockhist, const float* __restrict__ out2q,
    u32* __restrict__ rowlist, const float* __restrict__ Ni,
    float* __restrict__ out3, int q)
{
  __shared__ int wtot[4];
  __shared__ int cur[1024];
  int tid = threadIdx.x, b = blockIdx.x, lane = tid & 63, w = tid >> 6;
  const ushort4* bh4 = (const ushort4*)blockhist;
  int tot[4] = {0,0,0,0}, pre[4] = {0,0,0,0};
  for (int bb = 0; bb < 32; ++bb){
    ushort4 h = bh4[bb*256 + tid];
    if (bb < b){ pre[0]+=h.x; pre[1]+=h.y; pre[2]+=h.z; pre[3]+=h.w; }
    tot[0]+=h.x; tot[1]+=h.y; tot[2]+=h.z; tot[3]+=h.w;
  }
  int s = tot[0]+tot[1]+tot[2]+tot[3];
  int v = s;
  #pragma unroll
  for (int d = 1; d < 64; d <<= 1){
    int o = __shfl_up(v, d, 64);
    if (lane >= d) v += o;
  }
  if (lane == 63) wtot[w] = v;
  __syncthreads();
  int woff = 0;
  #pragma unroll
  for (int ww = 0; ww < 4; ++ww) if (ww < w) woff += wtot[ww];
  int base = woff + v - s;
  if (b == 0){
    const int qb = q << 10;
    out3[qb + 4*tid+0] = Ni[qb + 4*tid+0]*GAMMA_F + (float)tot[0]*OMG_F;
    out3[qb + 4*tid+1] = Ni[qb + 4*tid+1]*GAMMA_F + (float)tot[1]*OMG_F;
    out3[qb + 4*tid+2] = Ni[qb + 4*tid+2]*GAMMA_F + (float)tot[2]*OMG_F;
    out3[qb + 4*tid+3] = Ni[qb + 4*tid+3]*GAMMA_F + (float)tot[3]*OMG_F;
  }
  cur[4*tid+0] = base + pre[0];
  cur[4*tid+1] = base + tot[0] + pre[1];
  cur[4*tid+2] = base + tot[0]+tot[1] + pre[2];
  cur[4*tid+3] = base + tot[0]+tot[1]+tot[2] + pre[3];
  __syncthreads();
  #pragma unroll
  for (int j = 0; j < 4; ++j){
    int row = b*1024 + tid + 256*j;
    int c = (int)out2q[row];
    int pos = atomicAdd(&cur[c], 1);
    rowlist[pos] = (u32)row | ((u32)c << 16);
  }
}

// ---------- update: 2048 1-wave blocks, 16 slots, FULL preload ----------
// LAST=1 (q=7): skip residual writeback + rnorm (logits applies final subtract).
template<int LAST>
__global__ __launch_bounds__(64, 2) void update_kernel(
    f16* __restrict__ AH, f16* __restrict__ AL,
    const u32* __restrict__ rowlist, const float* __restrict__ codebooks,
    float* __restrict__ out4, float* __restrict__ rnorm, int q)
{
  const int lane = threadIdx.x;
  const int s0 = blockIdx.x * 16;
  u32 mypk = 0;
  if (lane < 16) mypk = rowlist[s0 + lane];
  int rows[16], codes[16];
  #pragma unroll
  for (int s = 0; s < 16; ++s){
    u32 pk = (u32)__shfl((int)mypk, s, 64);
    rows[s] = (int)(pk & 0xFFFFu);
    codes[s] = (int)(pk >> 16);
  }
  // preload all rows (and W rows if needed) — one round trip
  f16x4 H[16], L[16];
  #pragma unroll
  for (int s = 0; s < 16; ++s){
    size_t base = (size_t)rows[s] * 256 + lane*4;
    H[s] = *(const f16x4*)(AH + base);
    L[s] = *(const f16x4*)(AL + base);
  }
  float4 W4[16];
  if (!LAST){
    #pragma unroll
    for (int s = 0; s < 16; ++s)
      W4[s] = *(const float4*)&codebooks[(((size_t)q << 10) + codes[s])*256 + lane*4];
  }
  float vs[4] = {0.f, 0.f, 0.f, 0.f};
  #pragma unroll
  for (int s = 0; s < 16; ++s){
    if (s > 0 && codes[s] != codes[s-1]){
      float* dst = out4 + (((size_t)q << 10) + codes[s-1])*256 + lane*4;
      #pragma unroll
      for (int t = 0; t < 4; ++t) atomicAdd(dst + t, vs[t] * OMG_F);
      vs[0] = vs[1] = vs[2] = vs[3] = 0.f;
    }
    float p = 0.f;
    f16x4 nh, nl;
    #pragma unroll
    for (int t = 0; t < 4; ++t){
      float rj = (float)H[s][t] + (float)L[s][t] * LO_INV;
      vs[t] += rj;
      if (!LAST){
        float rn_ = rj - W4[s][t];
        f16 hh = (f16)rn_;
        nh[t] = hh;
        nl[t] = (f16)((rn_ - (float)hh) * LO_SCALE);
        p += rn_ * rn_;
      }
    }
    if (!LAST){
      size_t base = (size_t)rows[s] * 256 + lane*4;
      *(f16x4*)(AH + base) = nh;
      *(f16x4*)(AL + base) = nl;
      #pragma unroll
      for (int o = 32; o > 0; o >>= 1) p += __shfl_down(p, o, 64);
      if (lane == 0) rnorm[rows[s]] = p;
    }
  }
  {
    float* dst = out4 + (((size_t)q << 10) + codes[15])*256 + lane*4;
    #pragma unroll
    for (int t = 0; t < 4; ++t) atomicAdd(dst + t, vs[t] * OMG_F);
  }
}

// ---------- epilogue: logits = data - (r7 - W7[c7]), loss ----------
__global__ __launch_bounds__(256) void logits_loss_kernel(
    const float* __restrict__ data, const f16* __restrict__ AH, const f16* __restrict__ AL,
    const float* __restrict__ out2q7, const float* __restrict__ W7,
    float* __restrict__ out0, float* __restrict__ out1)
{
  __shared__ float rs[32][257];
  int blk = blockIdx.x, b = blk >> 6, s0 = (blk & 63) * 32;
  int tid = threadIdx.x;
  int r0 = blk*32;
  int c2 = tid >> 3, k0 = (tid & 7) * 32;
  int grow = r0 + c2;
  int code = (int)out2q7[grow];
  const float* wrow = W7 + (size_t)code * 256 + k0;
  #pragma unroll
  for (int jc = 0; jc < 4; ++jc){
    size_t off = (size_t)grow * 256 + k0 + jc*8;
    f16x8 h8 = *(const f16x8*)(AH + off);
    f16x8 l8 = *(const f16x8*)(AL + off);
    float4 w0 = *(const float4*)(wrow + jc*8);
    float4 w1 = *(const float4*)(wrow + jc*8 + 4);
    float wv[8] = {w0.x,w0.y,w0.z,w0.w, w1.x,w1.y,w1.z,w1.w};
    #pragma unroll
    for (int j = 0; j < 8; ++j)
      rs[c2][k0 + jc*8 + j] = ((float)h8[j] + (float)l8[j] * LO_INV) - wv[j];
  }
  __syncthreads();
  int c = tid & 31, g = tid >> 5;
  const float* dptr = data + (size_t)b * 524288 + s0;
  float* optr = out0 + (size_t)b * 524288 + s0;
  float lsum = 0.f;
  #pragma unroll 8
  for (int dd = 0; dd < 32; ++dd){
    int d = g*32 + dd;
    float r = rs[c][d];
    lsum += r*r;
    optr[(size_t)d * 2048 + c] = dptr[(size_t)d * 2048 + c] - r;
  }
  #pragma unroll
  for (int o = 32; o > 0; o >>= 1) lsum += __shfl_down(lsum, o, 64);
  if ((tid & 63) == 0) atomicAdd(out1, lsum * (1.0f / 8388608.0f));
}

// ---------- final: new_W = new_m / clip(new_N) ----------
__global__ __launch_bounds__(256) void out5_kernel(const float* __restrict__ out4,
                                                   const float* __restrict__ out3,
                                                   float* __restrict__ out5){
  int e4 = blockIdx.x*256 + threadIdx.x;
  float Nn = fmaxf(out3[e4 >> 6], 1e-8f);
  float4 v = ((const float4*)out4)[e4];
  v.x /= Nn; v.y /= Nn; v.z /= Nn; v.w /= Nn;
  ((float4*)out5)[e4] = v;
}

extern "C" void kernel_launch(void* const* d_in, const int* in_sizes, int n_in,
                              void* d_out, int out_size, void* d_ws, size_t ws_size,
                              hipStream_t stream){
  float* out = (float*)d_out;

  // size-keyed input binding
  const float* data = nullptr; const float* codebooks = nullptr;
  const float* Ni = nullptr;   const float* mi = nullptr;
  for (int i = 0; i < n_in; ++i){
    if      (in_sizes[i] == 8388608) data = (const float*)d_in[i];
    else if (in_sizes[i] == 8192)    Ni   = (const float*)d_in[i];
    else if (in_sizes[i] == 2097152){
      if (!codebooks) codebooks = (const float*)d_in[i];
      else            mi        = (const float*)d_in[i];
    }
  }
  if (!data || !codebooks || !Ni || !mi){
    sentinel_kernel<<<1, 64, 0, stream>>>(out, 6666.0f);
    return;
  }

  // ws layout (bytes):
  // AH 16,777,216 | AL 16,777,216 | whl 8,388,608 | wnorm 32,768 | rnorm 131,072 |
  // blockhist 65,536 | rowlist(u32) 131,072 | keybuf 262,144 = 42,565,632
  const size_t ws_need = 42565632ull;
  if (ws_size < ws_need){
    sentinel_kernel<<<1, 64, 0, stream>>>(out, 7777.0f);
    return;
  }
  f16*   AH     = (f16*)d_ws;
  f16*   AL     = AH + 8388608;
  f16*   whl    = AL + 8388608;
  float* wnormb = (float*)(whl + 4194304);
  float* rnorm  = wnormb + 8192;
  unsigned short* blockhist = (unsigned short*)(rnorm + 32768);
  u32*   rowlist = (u32*)(blockhist + 32768);
  u64*   keybuf  = (u64*)(rowlist + 32768);

  // out offsets (fp32, reference return order)
  float* out0 = out;                  // logits  8388608
  float* out1 = out0 + 8388608;       // loss    1
  float* out2 = out1 + 1;             // indices 262144
  float* out3 = out2 + 262144;        // new_N   8192
  float* out4 = out3 + 8192;          // new_m   2097152
  float* out5 = out4 + 2097152;       // new_W   2097152

  hipMemsetAsync(out1, 0, sizeof(float), stream);
  hipMemsetAsync(keybuf, 0xFF, 262144, stream);

  wsplit_kernel<<<dim3(4096), 64, 0, stream>>>(codebooks, whl);
  rownorm_kernel<<<dim3(8192), 64, 0, stream>>>(codebooks, wnormb, 8192);
  init_kernel<<<dim3(1024), 256, 0, stream>>>(data, AH, AL, rnorm);
  out4init_kernel<<<dim3(2048), 256, 0, stream>>>(mi, out4);

  for (int q = 0; q < 8; ++q){
    float* out2q = out2 + (size_t)q * 32768;
    dist_kernel<<<dim3(256, 4), 256, 0, stream>>>(AH, AL, whl, wnormb, rnorm, keybuf, q);
    hist_kernel<<<dim3(32), 256, 0, stream>>>(keybuf, out2q, blockhist);
    scanscatter_kernel<<<dim3(32), 256, 0, stream>>>(blockhist, out2q, rowlist,
                                                     Ni, out3, q);
    if (q < 7)
      update_kernel<0><<<dim3(2048), 64, 0, stream>>>(AH, AL, rowlist,
                                                      codebooks, out4, rnorm, q);
    else
      update_kernel<1><<<dim3(2048), 64, 0, stream>>>(AH, AL, rowlist,
                                                      codebooks, out4, rnorm, q);
  }

  logits_loss_kernel<<<dim3(1024), 256, 0, stream>>>(data, AH, AL,
                                                     out2 + 7*32768,
                                                     codebooks + 7*262144,
                                                     out0, out1);
  out5_kernel<<<dim3(2048), 256, 0, stream>>>(out4, out3, out5);
}